// Round 5
// baseline (785.608 us; speedup 1.0000x reference)
//
#include <hip/hip_runtime.h>
#include <hip/hip_cooperative_groups.h>
#include <stdint.h>

namespace cg = cooperative_groups;

// ---------------- problem constants ----------------
#define K_TOTAL   98304u     // 32 * 512 * 6
#define EMA_RATE  0.003f

// ---------------- config ----------------
#define GRID_BLOCKS   1024
#define BLOCK_THREADS 256
#define NWAVES        4096   // GRID_BLOCKS*BLOCK_THREADS/64
#define WCAP          256    // per-wave candidate slots (mean ~85, >10 sigma)

#define SBINS         4096   // sample hist bins = top 12 bits of key
#define SSHIFT        20
#define SAMPLE_V4     16384  // 65536 floats sampled (1/384 of data)
#define SAMPLE_BLOCKS 32     // 512 float4 per sampling block
#define STARGET       640u   // ~2.5x K at full scale, + margin bin below

#define CBINS         4096   // candidate hist bins
#define CSHIFT        12     // bin width = 4096 keys
#define CAP2          16384u // bin-g* candidate cap
#define OCAP          65536u // overflow spill cap
#define EQCAP         256    // tie buffer

// monotone float->uint key: order(key) == order(float)
__device__ __forceinline__ unsigned f2key(float x) {
    unsigned u = __float_as_uint(x);
    return (u & 0x80000000u) ? ~u : (u | 0x80000000u);
}
__device__ __forceinline__ float key2f(unsigned key) {
    unsigned u = (key & 0x80000000u) ? (key & 0x7FFFFFFFu) : ~key;
    return __uint_as_float(u);
}

// ctrs layout: [0]=ocnt  [1]=cnt2  [2]=base  [3]=gstar  [4]=need2
__global__ __launch_bounds__(BLOCK_THREADS) void topk_all(
        const float4* __restrict__ in, float4* __restrict__ out4,
        float* __restrict__ out,
        unsigned* __restrict__ shist, unsigned* __restrict__ ghist,
        unsigned* __restrict__ ctrs,  unsigned* __restrict__ wcnt,
        uint2* __restrict__ wreg,     uint2* __restrict__ ovf,
        unsigned* __restrict__ kval2, unsigned* __restrict__ cidx2,
        const float* __restrict__ thr_in, int nvec)
{
    cg::grid_group grid = cg::this_grid();
    __shared__ unsigned h[CBINS];          // 16 KB, reused by 3 phases
    __shared__ unsigned psum[BLOCK_THREADS];
    __shared__ unsigned eqidx[EQCAP];
    __shared__ unsigned eqcnt;
    __shared__ unsigned sh_low, sh_need3;

    const unsigned t    = threadIdx.x;
    const unsigned gtid = blockIdx.x * BLOCK_THREADS + t;

    // ---------------- P0: zero all globals we accumulate into --------------
    if (gtid < SBINS)                   shist[gtid] = 0;
    else if (gtid < 2 * SBINS)          ghist[gtid - SBINS] = 0;
    else if (gtid < 2 * SBINS + 8)      ctrs[gtid - 2 * SBINS] = 0;
    grid.sync();

    // ---------------- P1: sample histogram (blocks 0..31, 64K floats) ------
    if (blockIdx.x < SAMPLE_BLOCKS) {
        for (int i = t; i < SBINS; i += BLOCK_THREADS) h[i] = 0;
        __syncthreads();
        unsigned s0 = blockIdx.x * 512 + t;
        #pragma unroll
        for (int u = 0; u < 2; ++u) {
            float4 v = in[s0 + u * 256];
            atomicAdd(&h[f2key(v.x) >> SSHIFT], 1u);
            atomicAdd(&h[f2key(v.y) >> SSHIFT], 1u);
            atomicAdd(&h[f2key(v.z) >> SSHIFT], 1u);
            atomicAdd(&h[f2key(v.w) >> SSHIFT], 1u);
        }
        __syncthreads();
        for (int i = t; i < SBINS; i += BLOCK_THREADS) {
            unsigned c = h[i];
            if (c) atomicAdd(&shist[i], c);    // sparse: ~500 nonzero bins
        }
    }
    grid.sync();

    // ---------------- P2: pick conservative base key (block 0) -------------
    if (blockIdx.x == 0) {
        const int GB = SBINS / BLOCK_THREADS;   // 16 bins/thread, descending
        int hi = SBINS - 1 - t * GB;
        unsigned c[GB];
        #pragma unroll
        for (int j = 0; j < GB; ++j) c[j] = shist[hi - j];
        unsigned s = 0;
        #pragma unroll
        for (int j = 0; j < GB; ++j) s += c[j];
        psum[t] = s;
        __syncthreads();
        for (int off = 1; off < BLOCK_THREADS; off <<= 1) {
            unsigned o = (t >= off) ? psum[t - off] : 0u;
            __syncthreads();
            psum[t] += o;
            __syncthreads();
        }
        unsigned cum = psum[t] - s;
        for (int j = 0; j < GB; ++j) {
            if (cum < STARGET && cum + c[j] >= STARGET) {
                unsigned bin = (unsigned)(hi - j);
                unsigned bb = (bin > 0) ? bin - 1 : 0;   // one margin bin
                ctrs[2] = bb << SSHIFT;                  // base key
            }
            cum += c[j];
        }
    }
    grid.sync();

    // ---------------- P3: main stream — zero out, compact, LDS cand-hist ---
    {
        for (int i = t; i < CBINS; i += BLOCK_THREADS) h[i] = 0;
        __syncthreads();
        unsigned base = ctrs[2];
        unsigned nth  = GRID_BLOCKS * BLOCK_THREADS;
        unsigned gw   = gtid >> 6;
        unsigned lane = t & 63u;
        uint2* wb = wreg + (size_t)gw * WCAP;
        unsigned wcount = 0;
        const float4 z4 = make_float4(0.f, 0.f, 0.f, 0.f);
        for (unsigned i = gtid; i < (unsigned)nvec; i += nth) {
            float4 v = in[i];
            out4[i] = z4;                      // fused output zeroing
            unsigned idx = 4u * i;
            float xs[4] = {v.x, v.y, v.z, v.w};
            #pragma unroll
            for (int c = 0; c < 4; ++c) {
                unsigned key = f2key(xs[c]);
                bool pred = key >= base;
                unsigned long long mask = __ballot(pred);
                if (mask) {                    // wave-uniform, ~55% taken
                    if (pred) {
                        unsigned prefix = __builtin_amdgcn_mbcnt_hi(
                            (unsigned)(mask >> 32),
                            __builtin_amdgcn_mbcnt_lo((unsigned)mask, 0u));
                        unsigned off = wcount + prefix;
                        unsigned g = (key - base) >> CSHIFT;
                        if (g > CBINS - 1) g = CBINS - 1;
                        atomicAdd(&h[g], 1u);  // only ~1.3% of elements
                        if (off < WCAP) {
                            wb[off] = make_uint2(key, idx + c);
                        } else {               // never-taken safety spill
                            unsigned q = atomicAdd(&ctrs[0], 1u);
                            if (q < OCAP) ovf[q] = make_uint2(key, idx + c);
                        }
                    }
                    wcount += (unsigned)__popcll(mask);
                }
            }
        }
        if (lane == 0) wcnt[gw] = (wcount < WCAP) ? wcount : WCAP;
        __syncthreads();
        for (int i = t; i < CBINS; i += BLOCK_THREADS) {
            unsigned c = h[i];
            if (c) atomicAdd(&ghist[i], c);    // sparse merge
        }
    }
    grid.sync();

    // ---------------- P4: scan candidate hist -> g*, need2 (block 0) -------
    if (blockIdx.x == 0) {
        const int GB = CBINS / BLOCK_THREADS;   // 16
        int hi = CBINS - 1 - t * GB;
        unsigned c[GB];
        #pragma unroll
        for (int j = 0; j < GB; ++j) c[j] = ghist[hi - j];
        unsigned s = 0;
        #pragma unroll
        for (int j = 0; j < GB; ++j) s += c[j];
        psum[t] = s;
        __syncthreads();
        for (int off = 1; off < BLOCK_THREADS; off <<= 1) {
            unsigned o = (t >= off) ? psum[t - off] : 0u;
            __syncthreads();
            psum[t] += o;
            __syncthreads();
        }
        unsigned cum = psum[t] - s;
        for (int j = 0; j < GB; ++j) {
            if (cum < K_TOTAL && cum + c[j] >= K_TOTAL) {
                ctrs[3] = (unsigned)(hi - j);   // g*
                ctrs[4] = K_TOTAL - cum;        // need2 inside bin g*
            }
            cum += c[j];
        }
    }
    grid.sync();

    // ---------------- P5: scatter winners, compact bin-g* ------------------
    {
        unsigned base  = ctrs[2];
        unsigned gstar = ctrs[3];
        unsigned slot0 = blockIdx.x * 4 * WCAP;    // this block's 4 waves
        for (unsigned j = t; j < 4 * WCAP; j += BLOCK_THREADS) {
            unsigned w = (slot0 + j) >> 8;         // WCAP == 256
            if ((j & 255u) < wcnt[w]) {
                uint2 e = wreg[slot0 + j];
                unsigned g = (e.x - base) >> CSHIFT;
                if (g > CBINS - 1) g = CBINS - 1;
                if (g > gstar) {
                    out[e.y] = fmaxf(key2f(e.x), 0.0f);    // definite winner
                } else if (g == gstar) {
                    unsigned p = atomicAdd(&ctrs[1], 1u);
                    if (p < CAP2) { kval2[p] = e.x; cidx2[p] = e.y; }
                }
            }
        }
        if (blockIdx.x == 0) {                     // overflow list (expected 0)
            unsigned no = min(ctrs[0], (unsigned)OCAP);
            for (unsigned s = t; s < no; s += BLOCK_THREADS) {
                uint2 e = ovf[s];
                unsigned g = (e.x - base) >> CSHIFT;
                if (g > CBINS - 1) g = CBINS - 1;
                if (g > gstar) {
                    out[e.y] = fmaxf(key2f(e.x), 0.0f);
                } else if (g == gstar) {
                    unsigned p = atomicAdd(&ctrs[1], 1u);
                    if (p < CAP2) { kval2[p] = e.x; cidx2[p] = e.y; }
                }
            }
        }
    }
    grid.sync();

    // ---------------- P6: exact kth key, ties, EMA (block 0) ---------------
    if (blockIdx.x == 0) {
        unsigned nc2   = min(ctrs[1], (unsigned)CAP2);
        unsigned base3 = ctrs[2] + (ctrs[3] << CSHIFT);
        unsigned need2 = ctrs[4];
        const int NB = 1 << CSHIFT;               // 4096 exact keys

        for (int i = t; i < NB; i += BLOCK_THREADS) h[i] = 0;
        if (t == 0) eqcnt = 0;
        __syncthreads();
        for (unsigned i = t; i < nc2; i += BLOCK_THREADS) {
            unsigned low = kval2[i] - base3;
            if (low > (unsigned)(NB - 1)) low = NB - 1;
            atomicAdd(&h[low], 1u);
        }
        __syncthreads();

        const int GB = NB / BLOCK_THREADS;        // 16
        int hi = NB - 1 - t * GB;
        unsigned s = 0;
        for (int j = 0; j < GB; ++j) s += h[hi - j];
        psum[t] = s;
        __syncthreads();
        for (int off = 1; off < BLOCK_THREADS; off <<= 1) {
            unsigned o = (t >= off) ? psum[t - off] : 0u;
            __syncthreads();
            psum[t] += o;
            __syncthreads();
        }
        unsigned cum = psum[t] - s;
        for (int j = 0; j < GB; ++j) {
            unsigned c = h[hi - j];
            if (cum < need2 && cum + c >= need2) {
                sh_low = (unsigned)(hi - j);
                sh_need3 = need2 - cum;           // ties accepted at kth key
            }
            cum += c;
        }
        __syncthreads();
        unsigned kth_key = base3 + sh_low;
        unsigned need3   = sh_need3;

        for (unsigned i = t; i < nc2; i += BLOCK_THREADS) {
            unsigned key = kval2[i];
            if (key > kth_key) {
                out[cidx2[i]] = fmaxf(key2f(key), 0.0f);
            } else if (key == kth_key) {
                unsigned p = atomicAdd(&eqcnt, 1u);
                if (p < EQCAP) eqidx[p] = cidx2[i];
            }
        }
        __syncthreads();

        // tie-break: lax.top_k picks lowest flat indices first
        unsigned ne = min(eqcnt, (unsigned)EQCAP);
        float vv = key2f(kth_key);
        for (unsigned e = t; e < ne; e += BLOCK_THREADS) {
            unsigned my = eqidx[e];
            unsigned rank = 0;
            for (unsigned f = 0; f < ne; ++f) rank += (eqidx[f] < my) ? 1u : 0u;
            if (rank < need3) out[my] = fmaxf(vv, 0.0f);
        }

        if (t == 0) {
            float mink = fmaxf(vv, 0.0f);         // relu(k-th largest)
            out[4 * (size_t)nvec] =
                (1.0f - EMA_RATE) * thr_in[0] + EMA_RATE * mink;
        }
    }
}

// ---------------- launch ----------------
extern "C" void kernel_launch(void* const* d_in, const int* in_sizes, int n_in,
                              void* d_out, int out_size, void* d_ws, size_t ws_size,
                              hipStream_t stream) {
    const float4* feat   = (const float4*)d_in[0];
    const float*  thr_in = (const float*)d_in[1];
    float*  out  = (float*)d_out;
    float4* out4 = (float4*)d_out;
    int N    = in_sizes[0];      // 25165824
    int nvec = N / 4;

    // ---- workspace layout ----
    uint8_t* w = (uint8_t*)d_ws;
    unsigned* shist = (unsigned*)w;                          // 16 KB
    unsigned* ghist = (unsigned*)(w + (16 << 10));           // 16 KB
    unsigned* ctrs  = (unsigned*)(w + (32 << 10));           // 32 B
    unsigned* wcnt  = (unsigned*)(w + (36 << 10));           // 16 KB
    uint2*    wreg  = (uint2*)(w + ((size_t)1 << 20));       // 8 MB
    uint2*    ovf   = (uint2*)(w + ((size_t)10 << 20));      // 512 KB
    unsigned* kval2 = (unsigned*)(w + ((size_t)11 << 20));   // 64 KB
    unsigned* cidx2 = (unsigned*)(w + ((size_t)11 << 20) + CAP2 * 4);

    void* args[] = {
        (void*)&feat, (void*)&out4, (void*)&out,
        (void*)&shist, (void*)&ghist, (void*)&ctrs, (void*)&wcnt,
        (void*)&wreg, (void*)&ovf, (void*)&kval2, (void*)&cidx2,
        (void*)&thr_in, (void*)&nvec
    };
    hipLaunchCooperativeKernel((void*)topk_all,
                               dim3(GRID_BLOCKS), dim3(BLOCK_THREADS),
                               args, 0, stream);
}

// Round 6
// 245.430 us; speedup vs baseline: 3.2009x; 3.2009x over previous
//
#include <hip/hip_runtime.h>
#include <stdint.h>

// ---------------- problem constants ----------------
#define K_TOTAL   98304u     // 32 * 512 * 6
#define EMA_RATE  0.003f

// ---------------- select config ----------------
#define SBINS      4096      // sample hist bins (top 12 bits of key)
#define SSHIFT     20
#define SAMPLE_V4  16384     // 65536 floats sampled (1/384 of data)
#define STARGET    640u      // ~2.5x K at full scale, + one margin bin below

#define CBINS      4096      // candidate hist bins
#define CSHIFT     12        // bin width = 4096 keys
#define CAP2       16384u    // bin-g* candidate cap
#define OCAP       65536u    // overflow spill cap
#define EQCAP      256       // tie buffer

#define MP_BLOCKS  1024
#define MP_THREADS 256
#define MP_U       24        // 1024*256*24 float4 = 6291456 = nvec exactly
#define NWAVES     4096      // MP_BLOCKS*MP_THREADS/64
#define WCAP       256       // per-wave candidate slots (mean ~60-140)

// monotone float->uint key: order(key) == order(float)
__device__ __forceinline__ unsigned f2key(float x) {
    unsigned u = __float_as_uint(x);
    return (u & 0x80000000u) ? ~u : (u | 0x80000000u);
}
__device__ __forceinline__ float key2f(unsigned key) {
    unsigned u = (key & 0x80000000u) ? (key & 0x7FFFFFFFu) : ~key;
    return __uint_as_float(u);
}

// ctrs: [0]=ocnt  [1]=cnt2  [2]=base key  [3]=gstar  [4]=need2

// ---------------- S1: sample histogram (first 256 KB, iid data) ------------
__global__ __launch_bounds__(256) void sample_hist_kernel(
        const float4* __restrict__ in, unsigned* __restrict__ shist) {
    __shared__ unsigned h[SBINS];
    for (int i = threadIdx.x; i < SBINS; i += 256) h[i] = 0;
    __syncthreads();
    unsigned s0 = blockIdx.x * 512 + threadIdx.x;   // 32 blocks * 512 float4
    #pragma unroll
    for (int u = 0; u < 2; ++u) {
        float4 v = in[s0 + u * 256];
        atomicAdd(&h[f2key(v.x) >> SSHIFT], 1u);
        atomicAdd(&h[f2key(v.y) >> SSHIFT], 1u);
        atomicAdd(&h[f2key(v.z) >> SSHIFT], 1u);
        atomicAdd(&h[f2key(v.w) >> SSHIFT], 1u);
    }
    __syncthreads();
    for (int i = threadIdx.x; i < SBINS; i += 256) {
        unsigned c = h[i];
        if (c) atomicAdd(&shist[i], c);       // sparse: ~500 nonzero bins
    }
}

// ---------------- S2: pick conservative base key ---------------------------
__global__ __launch_bounds__(256) void sample_scan_kernel(
        const unsigned* __restrict__ shist, unsigned* __restrict__ ctrs) {
    __shared__ unsigned psum[256];
    const int GB = SBINS / 256;               // 16 bins/thread, descending
    int t = threadIdx.x;
    int hi = SBINS - 1 - t * GB;
    unsigned c[GB];
    #pragma unroll
    for (int j = 0; j < GB; ++j) c[j] = shist[hi - j];
    unsigned s = 0;
    #pragma unroll
    for (int j = 0; j < GB; ++j) s += c[j];
    psum[t] = s;
    __syncthreads();
    for (int off = 1; off < 256; off <<= 1) {
        unsigned o = (t >= off) ? psum[t - off] : 0u;
        __syncthreads();
        psum[t] += o;
        __syncthreads();
    }
    unsigned cum = psum[t] - s;               // samples strictly above my group
    for (int j = 0; j < GB; ++j) {
        if (cum < STARGET && cum + c[j] >= STARGET) {
            unsigned bin = (unsigned)(hi - j);
            unsigned bb = (bin > 0) ? bin - 1 : 0;   // one margin bin
            ctrs[2] = bb << SSHIFT;                  // base key
        }
        cum += c[j];
    }
}

// ---------------- P: one-shot read stream + ballot compaction --------------
__global__ __launch_bounds__(MP_THREADS) void main_pass_kernel(
        const float4* __restrict__ in, unsigned* __restrict__ ctrs,
        uint2* __restrict__ wreg, unsigned* __restrict__ wcnt,
        uint2* __restrict__ ovf) {
    const unsigned gtid = blockIdx.x * MP_THREADS + threadIdx.x;
    const unsigned nth  = MP_BLOCKS * MP_THREADS;        // 262144
    float thresh = key2f(ctrs[2]);

    float4 v[MP_U];
    #pragma unroll
    for (int u = 0; u < MP_U; ++u) v[u] = in[gtid + u * nth];  // 24 loads, MLP
    __builtin_amdgcn_sched_barrier(0);        // pin loads above the branchy code

    unsigned gw = gtid >> 6;
    uint2* wb = wreg + (size_t)gw * WCAP;
    unsigned wcount = 0;
    #pragma unroll
    for (int u = 0; u < MP_U; ++u) {
        float xs[4] = {v[u].x, v[u].y, v[u].z, v[u].w};
        #pragma unroll
        for (int c = 0; c < 4; ++c) {
            bool pred = xs[c] >= thresh;      // float cmp ok: thresh > 0, no NaN
            unsigned long long mask = __ballot(pred);
            if (mask) {                        // ~59% of slots, wave-uniform
                if (pred) {
                    unsigned prefix = __builtin_amdgcn_mbcnt_hi(
                        (unsigned)(mask >> 32),
                        __builtin_amdgcn_mbcnt_lo((unsigned)mask, 0u));
                    unsigned off = wcount + prefix;
                    unsigned idx = 4u * (gtid + u * nth) + c;
                    if (off < WCAP) {
                        wb[off] = make_uint2(f2key(xs[c]), idx);
                    } else {                   // never-taken safety spill
                        unsigned q = atomicAdd(&ctrs[0], 1u);
                        if (q < OCAP) ovf[q] = make_uint2(f2key(xs[c]), idx);
                    }
                }
                wcount += (unsigned)__popcll(mask);
            }
        }
    }
    if ((threadIdx.x & 63u) == 0)
        wcnt[gw] = (wcount < WCAP) ? wcount : WCAP;
}

// ---------------- CH: histogram the compacted candidates -------------------
__global__ __launch_bounds__(256) void cand_hist_kernel(
        const uint2* __restrict__ wreg, const unsigned* __restrict__ wcnt,
        const uint2* __restrict__ ovf, const unsigned* __restrict__ ctrs,
        unsigned* __restrict__ ghist) {
    __shared__ unsigned h[CBINS];
    for (int i = threadIdx.x; i < CBINS; i += 256) h[i] = 0;
    __syncthreads();
    unsigned base = ctrs[2];
    unsigned tid = blockIdx.x * 256 + threadIdx.x;
    unsigned nth = gridDim.x * 256;
    const unsigned NSLOT = NWAVES * WCAP;
    for (unsigned s = tid; s < NSLOT; s += nth) {
        unsigned w = s >> 8;                   // WCAP == 256
        if ((s & 255u) < wcnt[w]) {
            unsigned g = (wreg[s].x - base) >> CSHIFT;
            if (g > CBINS - 1) g = CBINS - 1;
            atomicAdd(&h[g], 1u);
        }
    }
    unsigned no = min(ctrs[0], (unsigned)OCAP);
    for (unsigned s = tid; s < no; s += nth) {
        unsigned g = (ovf[s].x - base) >> CSHIFT;
        if (g > CBINS - 1) g = CBINS - 1;
        atomicAdd(&h[g], 1u);
    }
    __syncthreads();
    for (int i = threadIdx.x; i < CBINS; i += 256) {
        unsigned c = h[i];
        if (c) atomicAdd(&ghist[i], c);
    }
}

// ---------------- C2: scan candidate hist -> g*, need2 ---------------------
__global__ __launch_bounds__(256) void find_g_kernel(
        const unsigned* __restrict__ ghist, unsigned* __restrict__ ctrs) {
    __shared__ unsigned psum[256];
    const int GB = CBINS / 256;               // 16 bins/thread, descending
    int t = threadIdx.x;
    int hi = CBINS - 1 - t * GB;
    unsigned c[GB];
    #pragma unroll
    for (int j = 0; j < GB; ++j) c[j] = ghist[hi - j];
    unsigned s = 0;
    #pragma unroll
    for (int j = 0; j < GB; ++j) s += c[j];
    psum[t] = s;
    __syncthreads();
    for (int off = 1; off < 256; off <<= 1) {
        unsigned o = (t >= off) ? psum[t - off] : 0u;
        __syncthreads();
        psum[t] += o;
        __syncthreads();
    }
    unsigned cum = psum[t] - s;
    for (int j = 0; j < GB; ++j) {
        if (cum < K_TOTAL && cum + c[j] >= K_TOTAL) {
            ctrs[3] = (unsigned)(hi - j);     // g*
            ctrs[4] = K_TOTAL - cum;          // need2 inside bin g*
        }
        cum += c[j];
    }
}

// ---------------- C3: scatter definite winners, compact bin-g* -------------
__global__ __launch_bounds__(256) void scatter_kernel(
        const uint2* __restrict__ wreg, const unsigned* __restrict__ wcnt,
        const uint2* __restrict__ ovf, unsigned* __restrict__ ctrs,
        unsigned* __restrict__ kval2, unsigned* __restrict__ cidx2,
        float* __restrict__ out) {
    unsigned base  = ctrs[2];
    unsigned gstar = ctrs[3];
    unsigned tid = blockIdx.x * 256 + threadIdx.x;
    unsigned nth = gridDim.x * 256;
    const unsigned NSLOT = NWAVES * WCAP;
    for (unsigned s = tid; s < NSLOT; s += nth) {
        unsigned w = s >> 8;
        if ((s & 255u) < wcnt[w]) {
            uint2 e = wreg[s];
            unsigned g = (e.x - base) >> CSHIFT;
            if (g > CBINS - 1) g = CBINS - 1;
            if (g > gstar) {
                out[e.y] = fmaxf(key2f(e.x), 0.0f);      // definite winner
            } else if (g == gstar) {
                unsigned p = atomicAdd(&ctrs[1], 1u);
                if (p < CAP2) { kval2[p] = e.x; cidx2[p] = e.y; }
            }
        }
    }
    unsigned no = min(ctrs[0], (unsigned)OCAP);
    for (unsigned s = tid; s < no; s += nth) {
        uint2 e = ovf[s];
        unsigned g = (e.x - base) >> CSHIFT;
        if (g > CBINS - 1) g = CBINS - 1;
        if (g > gstar) {
            out[e.y] = fmaxf(key2f(e.x), 0.0f);
        } else if (g == gstar) {
            unsigned p = atomicAdd(&ctrs[1], 1u);
            if (p < CAP2) { kval2[p] = e.x; cidx2[p] = e.y; }
        }
    }
}

// ---------------- C4: exact select in 4096-key range, ties, EMA ------------
__global__ __launch_bounds__(256) void final_kernel(
        const unsigned* __restrict__ kval2, const unsigned* __restrict__ cidx2,
        const unsigned* __restrict__ ctrs, float* __restrict__ out,
        const float* __restrict__ thr_in, float* __restrict__ thr_out) {
    __shared__ unsigned h[1 << CSHIFT];       // one bin per exact key
    __shared__ unsigned psum[256];
    __shared__ unsigned eqidx[EQCAP];
    __shared__ unsigned eqcnt;
    __shared__ unsigned sh_low, sh_need3;
    const int NB = 1 << CSHIFT;               // 4096
    int t = threadIdx.x;
    unsigned nc2   = min(ctrs[1], (unsigned)CAP2);
    unsigned base3 = ctrs[2] + (ctrs[3] << CSHIFT);
    unsigned need2 = ctrs[4];

    for (int i = t; i < NB; i += 256) h[i] = 0;
    if (t == 0) eqcnt = 0;
    __syncthreads();
    for (unsigned i = t; i < nc2; i += 256) {
        unsigned low = kval2[i] - base3;
        if (low > (unsigned)(NB - 1)) low = NB - 1;
        atomicAdd(&h[low], 1u);
    }
    __syncthreads();

    const int GB = NB / 256;                  // 16 keys/thread, descending
    int hi = NB - 1 - t * GB;
    unsigned s = 0;
    for (int j = 0; j < GB; ++j) s += h[hi - j];
    psum[t] = s;
    __syncthreads();
    for (int off = 1; off < 256; off <<= 1) {
        unsigned o = (t >= off) ? psum[t - off] : 0u;
        __syncthreads();
        psum[t] += o;
        __syncthreads();
    }
    unsigned cum = psum[t] - s;
    for (int j = 0; j < GB; ++j) {
        unsigned c = h[hi - j];
        if (cum < need2 && cum + c >= need2) {
            sh_low = (unsigned)(hi - j);
            sh_need3 = need2 - cum;           // ties accepted at kth key
        }
        cum += c;
    }
    __syncthreads();
    unsigned kth_key = base3 + sh_low;
    unsigned need3   = sh_need3;

    for (unsigned i = t; i < nc2; i += 256) {
        unsigned key = kval2[i];
        if (key > kth_key) {
            out[cidx2[i]] = fmaxf(key2f(key), 0.0f);
        } else if (key == kth_key) {
            unsigned p = atomicAdd(&eqcnt, 1u);
            if (p < EQCAP) eqidx[p] = cidx2[i];
        }
    }
    __syncthreads();

    // tie-break: lax.top_k picks lowest flat indices first
    unsigned ne = min(eqcnt, (unsigned)EQCAP);
    float vv = key2f(kth_key);
    for (unsigned e = t; e < ne; e += 256) {
        unsigned my = eqidx[e];
        unsigned rank = 0;
        for (unsigned f = 0; f < ne; ++f) rank += (eqidx[f] < my) ? 1u : 0u;
        if (rank < need3) out[my] = fmaxf(vv, 0.0f);
    }

    if (t == 0) {
        float mink = fmaxf(vv, 0.0f);         // relu(k-th largest)
        thr_out[0] = (1.0f - EMA_RATE) * thr_in[0] + EMA_RATE * mink;
    }
}

// ---------------- launch ----------------
extern "C" void kernel_launch(void* const* d_in, const int* in_sizes, int n_in,
                              void* d_out, int out_size, void* d_ws, size_t ws_size,
                              hipStream_t stream) {
    const float4* feat   = (const float4*)d_in[0];
    const float*  thr_in = (const float*)d_in[1];
    float* out = (float*)d_out;
    int N = in_sizes[0];         // 25165824

    // ---- workspace layout ----
    uint8_t* w = (uint8_t*)d_ws;
    unsigned* shist = (unsigned*)w;                          // 16 KB
    unsigned* ghist = (unsigned*)(w + (16 << 10));           // 16 KB
    unsigned* ctrs  = (unsigned*)(w + (32 << 10));           // 64 B
    unsigned* wcnt  = (unsigned*)(w + (36 << 10));           // 16 KB
    uint2*    wreg  = (uint2*)(w + ((size_t)1 << 20));       // 8 MB
    uint2*    ovf   = (uint2*)(w + ((size_t)10 << 20));      // 512 KB
    unsigned* kval2 = (unsigned*)(w + ((size_t)11 << 20));   // 64 KB
    unsigned* cidx2 = (unsigned*)(w + ((size_t)11 << 20) + CAP2 * 4);

    // zero hists + ctrs (wcnt written unconditionally); zero the output
    hipMemsetAsync(d_ws, 0, (32 << 10) + 64, stream);
    hipMemsetAsync(d_out, 0, (size_t)N * 4, stream);

    sample_hist_kernel<<<32,  256, 0, stream>>>(feat, shist);
    sample_scan_kernel<<<1,   256, 0, stream>>>(shist, ctrs);
    main_pass_kernel  <<<MP_BLOCKS, MP_THREADS, 0, stream>>>(feat, ctrs,
                                                             wreg, wcnt, ovf);
    cand_hist_kernel  <<<128, 256, 0, stream>>>(wreg, wcnt, ovf, ctrs, ghist);
    find_g_kernel     <<<1,   256, 0, stream>>>(ghist, ctrs);
    scatter_kernel    <<<128, 256, 0, stream>>>(wreg, wcnt, ovf, ctrs,
                                                kval2, cidx2, out);
    final_kernel      <<<1,   256, 0, stream>>>(kval2, cidx2, ctrs,
                                                out, thr_in, out + N);
}